// Round 1
// baseline (158.454 us; speedup 1.0000x reference)
//
#include <hip/hip_runtime.h>

// Per-frame table build: M[f] = E0[f] @ inv([[R(r_f), t_f],[0,0,0,1]])
// Faithful to reference: vec2skew stacks columns, so K = skew(v)^T;
// n = |r| + 1e-15; a = sin(n)/n; b = (1-cos(n))/n^2; R = I + a*K + b*K^2,
// with K^2 = r r^T - |r|^2 I (exact). Rigid inverse: [[R^T, -R^T t],[0,0,0,1]].
__device__ __forceinline__ void compute_M(float rx, float ry, float rz,
                                          float tx, float ty, float tz,
                                          const float* __restrict__ E,
                                          float4* __restrict__ Mout) {
    float s = rx * rx + ry * ry + rz * rz;
    float n = sqrtf(s) + 1e-15f;
    float sn = sinf(n), cn = cosf(n);
    float A = sn / n;
    float B = (1.0f - cn) / (n * n);

    // R = I + A*K + B*(r r^T - s I),  K = [[0,rz,-ry],[-rz,0,rx],[ry,-rx,0]]
    float R00 = 1.0f + B * (rx * rx - s);
    float R01 =  A * rz + B * (rx * ry);
    float R02 = -A * ry + B * (rx * rz);
    float R10 = -A * rz + B * (rx * ry);
    float R11 = 1.0f + B * (ry * ry - s);
    float R12 =  A * rx + B * (ry * rz);
    float R20 =  A * ry + B * (rx * rz);
    float R21 = -A * rx + B * (ry * rz);
    float R22 = 1.0f + B * (rz * rz - s);

    // ext = inv(c2w): top-left = R^T, top-right u = -R^T t, bottom [0,0,0,1]
    float T00 = R00, T01 = R10, T02 = R20;
    float T10 = R01, T11 = R11, T12 = R21;
    float T20 = R02, T21 = R12, T22 = R22;
    float u0 = -(T00 * tx + T01 * ty + T02 * tz);
    float u1 = -(T10 * tx + T11 * ty + T12 * tz);
    float u2 = -(T20 * tx + T21 * ty + T22 * tz);

    // M = E0 @ ext (E0 bottom row is [0,0,0,1] but compute generally — cheap)
    #pragma unroll
    for (int i = 0; i < 4; ++i) {
        float e0 = E[4 * i + 0], e1 = E[4 * i + 1];
        float e2 = E[4 * i + 2], e3 = E[4 * i + 3];
        float m0 = e0 * T00 + e1 * T10 + e2 * T20;
        float m1 = e0 * T01 + e1 * T11 + e2 * T21;
        float m2 = e0 * T02 + e1 * T12 + e2 * T22;
        float m3 = e0 * u0 + e1 * u1 + e2 * u2 + e3;
        Mout[i] = make_float4(m0, m1, m2, m3);
    }
}

__global__ void build_table_kernel(const float* __restrict__ r,
                                   const float* __restrict__ t,
                                   const float* __restrict__ e0,
                                   float* __restrict__ M, int nf) {
    int f = blockIdx.x * blockDim.x + threadIdx.x;
    if (f >= nf) return;
    float4 m[4];
    compute_M(r[3 * f + 0], r[3 * f + 1], r[3 * f + 2],
              t[3 * f + 0], t[3 * f + 1], t[3 * f + 2],
              e0 + 16 * f, m);
    float4* Mo = reinterpret_cast<float4*>(M + 16 * f);
    Mo[0] = m[0]; Mo[1] = m[1]; Mo[2] = m[2]; Mo[3] = m[3];
}

// Gather: one thread per output float4 (row of the 4x4). Perfectly coalesced
// stores; 4 lanes of one ray broadcast-read the same cam_id; M table (640 KB)
// is L2-resident.
__global__ void gather_kernel(const int* __restrict__ cid,
                              const float4* __restrict__ M,
                              float4* __restrict__ out, int n4) {
    int tid = blockIdx.x * blockDim.x + threadIdx.x;
    if (tid >= n4) return;
    int ray = tid >> 2;
    int c = tid & 3;
    int cam = cid[ray];
    out[tid] = M[cam * 4 + c];
}

// Fallback (only if ws too small): fused per-ray compute.
__global__ void fused_kernel(const float* __restrict__ r,
                             const float* __restrict__ t,
                             const float* __restrict__ e0,
                             const int* __restrict__ cid,
                             float4* __restrict__ out, int nr) {
    int ray = blockIdx.x * blockDim.x + threadIdx.x;
    if (ray >= nr) return;
    int f = cid[ray];
    float4 m[4];
    compute_M(r[3 * f + 0], r[3 * f + 1], r[3 * f + 2],
              t[3 * f + 0], t[3 * f + 1], t[3 * f + 2],
              e0 + 16 * f, m);
    out[ray * 4 + 0] = m[0];
    out[ray * 4 + 1] = m[1];
    out[ray * 4 + 2] = m[2];
    out[ray * 4 + 3] = m[3];
}

extern "C" void kernel_launch(void* const* d_in, const int* in_sizes, int n_in,
                              void* d_out, int out_size, void* d_ws, size_t ws_size,
                              hipStream_t stream) {
    const float* r  = (const float*)d_in[0];   // (NF, 3)
    const float* t  = (const float*)d_in[1];   // (NF, 3)
    const float* e0 = (const float*)d_in[2];   // (NF, 4, 4)
    const int*  cid = (const int*)d_in[3];     // (NR,)
    float* out = (float*)d_out;                // (NR, 4, 4)

    const int nf = in_sizes[0] / 3;
    const int nr = in_sizes[3];
    const size_t table_bytes = (size_t)nf * 16 * sizeof(float);

    if (ws_size >= table_bytes) {
        float* M = (float*)d_ws;
        {
            int threads = 256;
            int blocks = (nf + threads - 1) / threads;
            build_table_kernel<<<blocks, threads, 0, stream>>>(r, t, e0, M, nf);
        }
        {
            int n4 = nr * 4;  // number of float4 rows in output
            int threads = 256;
            int blocks = (n4 + threads - 1) / threads;
            gather_kernel<<<blocks, threads, 0, stream>>>(
                cid, (const float4*)M, (float4*)out, n4);
        }
    } else {
        int threads = 256;
        int blocks = (nr + threads - 1) / threads;
        fused_kernel<<<blocks, threads, 0, stream>>>(
            r, t, e0, cid, (float4*)out, nr);
    }
}